// Round 4
// baseline (2496.910 us; speedup 1.0000x reference)
//
#include <hip/hip_runtime.h>

#define N_NODES 50000
#define N_EDGES 600000
#define IN_F 16
#define HF 128
#define NC 4
#define NHL 19
#define HS_STRIDE 36  // 32 k-chunk + pad; *4B = 144 bytes, 16B-aligned rows

__device__ __forceinline__ float lrelu(float x) { return x > 0.f ? x : 0.01f * x; }

// ---------------- CSR build ----------------

__global__ void count_deg_k(const int* __restrict__ dst, int* __restrict__ cnt) {
    int e = blockIdx.x * 256 + threadIdx.x;
    if (e < N_EDGES) atomicAdd(&cnt[dst[e]], 1);
}

__global__ void deginv_k(const int* __restrict__ cnt, float* __restrict__ dinv) {
    int v = blockIdx.x * 256 + threadIdx.x;
    if (v < N_NODES) dinv[v] = 1.0f / fmaxf((float)cnt[v], 1.0f);
}

// single-block exclusive scan via wave shuffles: 4 elements/thread, 4096/chunk
__global__ void scan_k(const int* __restrict__ cnt, int* __restrict__ rowptr) {
    __shared__ int wsum[16];
    __shared__ int carry_s;
    int t = threadIdx.x;
    int lane = t & 63, wid = t >> 6;
    if (t == 0) carry_s = 0;
    __syncthreads();
    for (int base = 0; base < N_NODES; base += 4096) {
        int idx = base + t * 4;
        int4 v = make_int4(0, 0, 0, 0);
        if (idx + 3 < N_NODES) v = *(const int4*)&cnt[idx];
        else {
            if (idx     < N_NODES) v.x = cnt[idx];
            if (idx + 1 < N_NODES) v.y = cnt[idx + 1];
            if (idx + 2 < N_NODES) v.z = cnt[idx + 2];
            if (idx + 3 < N_NODES) v.w = cnt[idx + 3];
        }
        int s1 = v.x + v.y, s2 = s1 + v.z, total = s2 + v.w;
        int sc = total;
#pragma unroll
        for (int off = 1; off < 64; off <<= 1) {
            int u = __shfl_up(sc, off, 64);
            if (lane >= off) sc += u;
        }
        if (lane == 63) wsum[wid] = sc;
        __syncthreads();
        if (t < 16) {
            int w = wsum[t];
#pragma unroll
            for (int off = 1; off < 16; off <<= 1) {
                int u = __shfl_up(w, off, 64);
                if (t >= off) w += u;
            }
            wsum[t] = w;
        }
        __syncthreads();
        int prefix = carry_s + (wid > 0 ? wsum[wid - 1] : 0) + (sc - total);
        if (idx     < N_NODES) rowptr[idx]     = prefix;
        if (idx + 1 < N_NODES) rowptr[idx + 1] = prefix + v.x;
        if (idx + 2 < N_NODES) rowptr[idx + 2] = prefix + s1;
        if (idx + 3 < N_NODES) rowptr[idx + 3] = prefix + s2;
        __syncthreads();
        if (t == 0) carry_s += wsum[15];
        __syncthreads();
    }
    if (t == 0) rowptr[N_NODES] = carry_s;
}

// fill CSR: int4 {src, bitcast(w), dst, 0}; also accumulate c[v] = sum of w into v
__global__ void fill_k(const int* __restrict__ src, const int* __restrict__ dst,
                       const float* __restrict__ ea, const int* __restrict__ rowptr,
                       int* __restrict__ fill, int4* __restrict__ edg,
                       const float* __restrict__ dinv, float* __restrict__ cacc) {
    int e = blockIdx.x * 256 + threadIdx.x;
    if (e < N_EDGES) {
        int d = dst[e];
        float w = ea[e] * dinv[d];
        int pos = rowptr[d] + atomicAdd(&fill[d], 1);
        edg[pos] = make_int4(src[e], __float_as_int(w), d, 0);
        atomicAdd(&cacc[d], w);
    }
}

// ---------------- O init: O[v][j] = c[v] * b[j] (bias via linearity; zero-base for atomics) ----

__global__ void init_k(float* __restrict__ O, const float* __restrict__ c,
                       const float* __restrict__ b) {
    int idx = blockIdx.x * 256 + threadIdx.x;  // float4 index
    int v = idx >> 5;
    if (v >= N_NODES) return;
    int j = (idx & 31) * 4;
    float cv = c[v];
    float4 bv = *(const float4*)&b[j];
    *(float4*)&O[(size_t)v * HF + j] =
        make_float4(cv * bv.x, cv * bv.y, cv * bv.z, cv * bv.w);
}

// ---------------- input GEMM: T[50000x128] = X[50000x16] @ W[16x128] (no bias) ----------------

__global__ void gemm_in_k(const float* __restrict__ X, const float* __restrict__ W,
                          float* __restrict__ T) {
    __shared__ float Ws[IN_F * HF];  // 8 KB
    int t = threadIdx.x;
    ((float4*)Ws)[t]       = ((const float4*)W)[t];
    ((float4*)Ws)[t + 256] = ((const float4*)W)[t + 256];
    __syncthreads();
    int row = blockIdx.x * 16 + (t >> 4);
    if (row >= N_NODES) return;
    int tx = t & 15;
    int c0 = tx * 4, c1 = 64 + tx * 4;
    float4 a0 = make_float4(0.f, 0.f, 0.f, 0.f);
    float4 a1 = make_float4(0.f, 0.f, 0.f, 0.f);
    const float4* xr = (const float4*)(X + row * IN_F);
#pragma unroll
    for (int k4 = 0; k4 < 4; k4++) {
        float4 xv = xr[k4];
        const float* xp = (const float*)&xv;
#pragma unroll
        for (int kk = 0; kk < 4; kk++) {
            int k = k4 * 4 + kk;
            float4 w0 = *(const float4*)&Ws[k * HF + c0];
            float4 w1 = *(const float4*)&Ws[k * HF + c1];
            float xs = xp[kk];
            a0.x = fmaf(xs, w0.x, a0.x); a0.y = fmaf(xs, w0.y, a0.y);
            a0.z = fmaf(xs, w0.z, a0.z); a0.w = fmaf(xs, w0.w, a0.w);
            a1.x = fmaf(xs, w1.x, a1.x); a1.y = fmaf(xs, w1.y, a1.y);
            a1.z = fmaf(xs, w1.z, a1.z); a1.w = fmaf(xs, w1.w, a1.w);
        }
    }
    *(float4*)&T[row * HF + c0] = a0;
    *(float4*)&T[row * HF + c1] = a1;
}

// ---------------- hidden GEMM: T = lrelu(H) @ W (no bias), 128x128 tile ----------------

__global__ __launch_bounds__(256) void gemm_h_k(const float* __restrict__ H,
                                                const float* __restrict__ W,
                                                float* __restrict__ T) {
    __shared__ float Ws[32 * HF];          // 16 KB
    __shared__ float Hs[128 * HS_STRIDE];  // 18 KB
    int t = threadIdx.x;
    int tx = t & 15, ty = t >> 4;
    int rbase = blockIdx.x * 128;
    int c0 = tx * 4, c1 = 64 + tx * 4;
    float acc[8][8];
#pragma unroll
    for (int i = 0; i < 8; i++)
#pragma unroll
        for (int j = 0; j < 8; j++) acc[i][j] = 0.f;
    int srow = t >> 3;
    int sc4  = t & 7;

    for (int kc = 0; kc < HF; kc += 32) {
        const float4* Wg = (const float4*)(W + kc * HF);
#pragma unroll
        for (int i = 0; i < 4; i++)
            ((float4*)Ws)[t + i * 256] = Wg[t + i * 256];
#pragma unroll
        for (int i = 0; i < 4; i++) {
            int rl = srow + i * 32;
            int row = rbase + rl;
            if (row >= N_NODES) row = N_NODES - 1;
            float4 v = *(const float4*)&H[row * HF + kc + sc4 * 4];
            v.x = lrelu(v.x); v.y = lrelu(v.y); v.z = lrelu(v.z); v.w = lrelu(v.w);
            *(float4*)&Hs[rl * HS_STRIDE + sc4 * 4] = v;
        }
        __syncthreads();
#pragma unroll
        for (int kq = 0; kq < 8; kq++) {
            float4 a[8];
#pragma unroll
            for (int i = 0; i < 8; i++)
                a[i] = *(const float4*)&Hs[(ty * 8 + i) * HS_STRIDE + kq * 4];
#pragma unroll
            for (int kk = 0; kk < 4; kk++) {
                int k = kq * 4 + kk;
                float4 w0 = *(const float4*)&Ws[k * HF + c0];
                float4 w1 = *(const float4*)&Ws[k * HF + c1];
                float wv[8] = {w0.x, w0.y, w0.z, w0.w, w1.x, w1.y, w1.z, w1.w};
#pragma unroll
                for (int i = 0; i < 8; i++) {
                    float av = ((const float*)&a[i])[kk];
#pragma unroll
                    for (int j = 0; j < 8; j++)
                        acc[i][j] = fmaf(av, wv[j], acc[i][j]);
                }
            }
        }
        __syncthreads();
    }
#pragma unroll
    for (int i = 0; i < 8; i++) {
        int row = rbase + ty * 8 + i;
        if (row < N_NODES) {
            *(float4*)&T[row * HF + c0] = make_float4(acc[i][0], acc[i][1], acc[i][2], acc[i][3]);
            *(float4*)&T[row * HF + c1] = make_float4(acc[i][4], acc[i][5], acc[i][6], acc[i][7]);
        }
    }
}

// ---------------- edge-parallel aggregation: O[dst] += w * T[src] ----------------
// One wave per 16 consecutive CSR edges (600000/16 = 37500 waves, exact).
// All 16 gathers issued back-to-back; wave-uniform segmented flush via fp32 atomics.

__global__ __launch_bounds__(256) void agg_ep_k(const float* __restrict__ T,
                                                float* __restrict__ O,
                                                const int4* __restrict__ edg) {
    int wv = __builtin_amdgcn_readfirstlane(blockIdx.x * 4 + (threadIdx.x >> 6));
    int base = wv * 16;
    int lane = threadIdx.x & 63;
    int f = lane * 2;
    int s[16], d[16];
    float w[16];
#pragma unroll
    for (int u = 0; u < 16; u++) {
        int4 ed = edg[base + u];
        s[u] = __builtin_amdgcn_readfirstlane(ed.x);
        w[u] = __int_as_float(__builtin_amdgcn_readfirstlane(ed.y));
        d[u] = __builtin_amdgcn_readfirstlane(ed.z);
    }
    float2 hv[16];
#pragma unroll
    for (int u = 0; u < 16; u++)
        hv[u] = *(const float2*)&T[(size_t)s[u] * HF + f];
    float ax = 0.f, ay = 0.f;
#pragma unroll
    for (int u = 0; u < 16; u++) {
        ax = fmaf(hv[u].x, w[u], ax);
        ay = fmaf(hv[u].y, w[u], ay);
        if (u == 15 || d[u + 1] != d[u]) {
            float* op = &O[(size_t)d[u] * HF + f];
            atomicAdd(op, ax);
            atomicAdd(op + 1, ay);
            ax = 0.f; ay = 0.f;
        }
    }
}

// ---------------- output layer: out = lrelu(H) @ Wfc + bfc ----------------

__global__ void fc_k(const float* __restrict__ H, const float* __restrict__ W,
                     const float* __restrict__ b, float* __restrict__ out) {
    int r = blockIdx.x * 256 + threadIdx.x;
    if (r >= N_NODES) return;
    float4 acc = *(const float4*)b;
    const float4* h4 = (const float4*)(H + r * HF);
    const float4* w4 = (const float4*)W;
#pragma unroll
    for (int k4 = 0; k4 < 32; k4++) {
        float4 hv = h4[k4];
        hv.x = lrelu(hv.x); hv.y = lrelu(hv.y); hv.z = lrelu(hv.z); hv.w = lrelu(hv.w);
        float4 wa = w4[k4 * 4 + 0], wb = w4[k4 * 4 + 1];
        float4 wc = w4[k4 * 4 + 2], wd = w4[k4 * 4 + 3];
        acc.x = fmaf(hv.x, wa.x, acc.x); acc.y = fmaf(hv.x, wa.y, acc.y);
        acc.z = fmaf(hv.x, wa.z, acc.z); acc.w = fmaf(hv.x, wa.w, acc.w);
        acc.x = fmaf(hv.y, wb.x, acc.x); acc.y = fmaf(hv.y, wb.y, acc.y);
        acc.z = fmaf(hv.y, wb.z, acc.z); acc.w = fmaf(hv.y, wb.w, acc.w);
        acc.x = fmaf(hv.z, wc.x, acc.x); acc.y = fmaf(hv.z, wc.y, acc.y);
        acc.z = fmaf(hv.z, wc.z, acc.z); acc.w = fmaf(hv.z, wc.w, acc.w);
        acc.x = fmaf(hv.w, wd.x, acc.x); acc.y = fmaf(hv.w, wd.y, acc.y);
        acc.z = fmaf(hv.w, wd.z, acc.z); acc.w = fmaf(hv.w, wd.w, acc.w);
    }
    *(float4*)&out[r * NC] = acc;
}

// ---------------- driver ----------------

extern "C" void kernel_launch(void* const* d_in, const int* in_sizes, int n_in,
                              void* d_out, int out_size, void* d_ws, size_t ws_size,
                              hipStream_t stream) {
    const float* X   = (const float*)d_in[0];
    const int*   EI  = (const int*)d_in[1];
    const float* EA  = (const float*)d_in[2];
    const float* Win = (const float*)d_in[3];
    const float* Wh  = (const float*)d_in[5];
    const float* bin = (const float*)d_in[4];
    const float* bh  = (const float*)d_in[6];
    const float* Wfc = (const float*)d_in[7];
    const float* bfc = (const float*)d_in[8];
    float* out = (float*)d_out;
    const int* src = EI;
    const int* dst = EI + N_EDGES;

    char* ws = (char*)d_ws;
    size_t off = 0;
    float* O    = (float*)(ws + off); off += (size_t)N_NODES * HF * 4;   // 25.6 MB
    float* T    = (float*)(ws + off); off += (size_t)N_NODES * HF * 4;   // 25.6 MB
    int4* edg   = (int4*)(ws + off);  off += (size_t)N_EDGES * 16;       // 9.6 MB
    int* rowptr = (int*)(ws + off);   off += (((size_t)(N_NODES + 1) * 4 + 15) / 16) * 16;
    int* cnt    = (int*)(ws + off);   off += (size_t)N_NODES * 4;
    int* fill   = (int*)(ws + off);   off += (size_t)N_NODES * 4;
    float* dinv = (float*)(ws + off); off += (size_t)N_NODES * 4;
    float* cacc = (float*)(ws + off); off += (size_t)N_NODES * 4;

    hipMemsetAsync(cnt, 0, N_NODES * 4, stream);
    hipMemsetAsync(fill, 0, N_NODES * 4, stream);
    hipMemsetAsync(cacc, 0, N_NODES * 4, stream);
    count_deg_k<<<(N_EDGES + 255) / 256, 256, 0, stream>>>(dst, cnt);
    deginv_k<<<(N_NODES + 255) / 256, 256, 0, stream>>>(cnt, dinv);
    scan_k<<<1, 1024, 0, stream>>>(cnt, rowptr);
    fill_k<<<(N_EDGES + 255) / 256, 256, 0, stream>>>(src, dst, EA, rowptr, fill, edg, dinv, cacc);

    const int initg = (N_NODES * 32 + 255) / 256;
    const int aggg  = (N_EDGES / 16 + 3) / 4;  // 9375 blocks

    // layer 1: T = X @ Win ; O = c*bin + Agg(T)
    gemm_in_k<<<(N_NODES + 15) / 16, 256, 0, stream>>>(X, Win, T);
    init_k<<<initg, 256, 0, stream>>>(O, cacc, bin);
    agg_ep_k<<<aggg, 256, 0, stream>>>(T, O, edg);
    // hidden layers: T = lrelu(O) @ W_l ; O = c*b_l + Agg(T)
    for (int l = 0; l < NHL; l++) {
        gemm_h_k<<<(N_NODES + 127) / 128, 256, 0, stream>>>(O, Wh + (size_t)l * HF * HF, T);
        init_k<<<initg, 256, 0, stream>>>(O, cacc, bh + (size_t)l * HF);
        agg_ep_k<<<aggg, 256, 0, stream>>>(T, O, edg);
    }
    fc_k<<<(N_NODES + 255) / 256, 256, 0, stream>>>(O, Wfc, bfc, out);
}

// Round 5
// 1549.270 us; speedup vs baseline: 1.6117x; 1.6117x over previous
//
#include <hip/hip_runtime.h>

#define N_NODES 50000
#define N_EDGES 600000
#define IN_F 16
#define HF 128
#define NC 4
#define NHL 19
#define HS_STRIDE 36  // 32 k-chunk + pad; breaks power-of-2 LDS strides

__device__ __forceinline__ float lrelu(float x) { return x > 0.f ? x : 0.01f * x; }

// ---------------- CSR build ----------------

__global__ void count_deg_k(const int* __restrict__ dst, int* __restrict__ cnt) {
    int e = blockIdx.x * 256 + threadIdx.x;
    if (e < N_EDGES) atomicAdd(&cnt[dst[e]], 1);
}

__global__ void deginv_k(const int* __restrict__ cnt, float* __restrict__ dinv) {
    int v = blockIdx.x * 256 + threadIdx.x;
    if (v < N_NODES) dinv[v] = 1.0f / fmaxf((float)cnt[v], 1.0f);
}

// single-block exclusive scan via wave shuffles: 4 elements/thread, 4096/chunk
__global__ void scan_k(const int* __restrict__ cnt, int* __restrict__ rowptr) {
    __shared__ int wsum[16];
    __shared__ int carry_s;
    int t = threadIdx.x;
    int lane = t & 63, wid = t >> 6;
    if (t == 0) carry_s = 0;
    __syncthreads();
    for (int base = 0; base < N_NODES; base += 4096) {
        int idx = base + t * 4;
        int4 v = make_int4(0, 0, 0, 0);
        if (idx + 3 < N_NODES) v = *(const int4*)&cnt[idx];
        else {
            if (idx     < N_NODES) v.x = cnt[idx];
            if (idx + 1 < N_NODES) v.y = cnt[idx + 1];
            if (idx + 2 < N_NODES) v.z = cnt[idx + 2];
            if (idx + 3 < N_NODES) v.w = cnt[idx + 3];
        }
        int s1 = v.x + v.y, s2 = s1 + v.z, total = s2 + v.w;
        int sc = total;
#pragma unroll
        for (int off = 1; off < 64; off <<= 1) {
            int u = __shfl_up(sc, off, 64);
            if (lane >= off) sc += u;
        }
        if (lane == 63) wsum[wid] = sc;
        __syncthreads();
        if (t < 16) {
            int w = wsum[t];
#pragma unroll
            for (int off = 1; off < 16; off <<= 1) {
                int u = __shfl_up(w, off, 64);
                if (t >= off) w += u;
            }
            wsum[t] = w;
        }
        __syncthreads();
        int prefix = carry_s + (wid > 0 ? wsum[wid - 1] : 0) + (sc - total);
        if (idx     < N_NODES) rowptr[idx]     = prefix;
        if (idx + 1 < N_NODES) rowptr[idx + 1] = prefix + v.x;
        if (idx + 2 < N_NODES) rowptr[idx + 2] = prefix + s1;
        if (idx + 3 < N_NODES) rowptr[idx + 3] = prefix + s2;
        __syncthreads();
        if (t == 0) carry_s += wsum[15];
        __syncthreads();
    }
    if (t == 0) rowptr[N_NODES] = carry_s;
}

// fill CSR: one int2 {src, bitcast(ea*dinv[dst])} store per edge
__global__ void fill_k(const int* __restrict__ src, const int* __restrict__ dst,
                       const float* __restrict__ ea, const int* __restrict__ rowptr,
                       int* __restrict__ fill, int2* __restrict__ edg,
                       const float* __restrict__ dinv) {
    int e = blockIdx.x * 256 + threadIdx.x;
    if (e < N_EDGES) {
        int d = dst[e];
        int pos = rowptr[d] + atomicAdd(&fill[d], 1);
        edg[pos] = make_int2(src[e], __float_as_int(ea[e] * dinv[d]));
    }
}

// ---------------- input GEMM: T[50000x128] = X[50000x16] @ W[16x128] + b ----------------

__global__ void gemm_in_k(const float* __restrict__ X, const float* __restrict__ W,
                          const float* __restrict__ b, float* __restrict__ T) {
    __shared__ float Ws[IN_F * HF];  // 8 KB
    int t = threadIdx.x;
    ((float4*)Ws)[t]       = ((const float4*)W)[t];
    ((float4*)Ws)[t + 256] = ((const float4*)W)[t + 256];
    __syncthreads();
    int row = blockIdx.x * 16 + (t >> 4);
    if (row >= N_NODES) return;
    int tx = t & 15;
    int c0 = tx * 4, c1 = 64 + tx * 4;
    float4 a0 = *(const float4*)&b[c0];
    float4 a1 = *(const float4*)&b[c1];
    const float4* xr = (const float4*)(X + row * IN_F);
#pragma unroll
    for (int k4 = 0; k4 < 4; k4++) {
        float4 xv = xr[k4];
        const float* xp = (const float*)&xv;
#pragma unroll
        for (int kk = 0; kk < 4; kk++) {
            int k = k4 * 4 + kk;
            float4 w0 = *(const float4*)&Ws[k * HF + c0];
            float4 w1 = *(const float4*)&Ws[k * HF + c1];
            float xs = xp[kk];
            a0.x = fmaf(xs, w0.x, a0.x); a0.y = fmaf(xs, w0.y, a0.y);
            a0.z = fmaf(xs, w0.z, a0.z); a0.w = fmaf(xs, w0.w, a0.w);
            a1.x = fmaf(xs, w1.x, a1.x); a1.y = fmaf(xs, w1.y, a1.y);
            a1.z = fmaf(xs, w1.z, a1.z); a1.w = fmaf(xs, w1.w, a1.w);
        }
    }
    *(float4*)&T[row * HF + c0] = a0;
    *(float4*)&T[row * HF + c1] = a1;
}

// ---------------- hidden GEMM: T = H @ W + b ----------------
// 64x128 tile (782 blocks -> ~3/CU, kills the 391-block wave quantization of 128x128),
// 256 threads, 4x8 acc/thread, 25 KB LDS.

__global__ __launch_bounds__(256) void gemm_h_k(const float* __restrict__ H,
                                                const float* __restrict__ W,
                                                const float* __restrict__ b,
                                                float* __restrict__ T) {
    __shared__ float Ws[32 * HF];         // 16 KB, k-major chunk
    __shared__ float Hs[64 * HS_STRIDE];  // 9 KB
    int t = threadIdx.x;
    int tx = t & 15, ty = t >> 4;         // tx: col group, ty: 0..15 row group
    int rbase = blockIdx.x * 64;
    int c0 = tx * 4, c1 = 64 + tx * 4;
    float4 b0 = *(const float4*)&b[c0];
    float4 b1 = *(const float4*)&b[c1];
    float acc[4][8];
#pragma unroll
    for (int i = 0; i < 4; i++) {
        acc[i][0] = b0.x; acc[i][1] = b0.y; acc[i][2] = b0.z; acc[i][3] = b0.w;
        acc[i][4] = b1.x; acc[i][5] = b1.y; acc[i][6] = b1.z; acc[i][7] = b1.w;
    }
    int srow = t >> 2;   // 0..63
    int sc4  = t & 3;    // 0..3

    for (int kc = 0; kc < HF; kc += 32) {
        const float4* Wg = (const float4*)(W + kc * HF);
#pragma unroll
        for (int i = 0; i < 4; i++)
            ((float4*)Ws)[t + i * 256] = Wg[t + i * 256];
        {
            int row = rbase + srow;
            if (row >= N_NODES) row = N_NODES - 1;  // clamp; stores guarded
            const float* hr = &H[(size_t)row * HF + kc];
            *(float4*)&Hs[srow * HS_STRIDE + sc4 * 4]      = *(const float4*)&hr[sc4 * 4];
            *(float4*)&Hs[srow * HS_STRIDE + 16 + sc4 * 4] = *(const float4*)&hr[16 + sc4 * 4];
        }
        __syncthreads();
#pragma unroll
        for (int kq = 0; kq < 8; kq++) {
            float4 a[4];
#pragma unroll
            for (int i = 0; i < 4; i++)
                a[i] = *(const float4*)&Hs[(ty * 4 + i) * HS_STRIDE + kq * 4];
#pragma unroll
            for (int kk = 0; kk < 4; kk++) {
                int k = kq * 4 + kk;
                float4 w0 = *(const float4*)&Ws[k * HF + c0];
                float4 w1 = *(const float4*)&Ws[k * HF + c1];
                float wv[8] = {w0.x, w0.y, w0.z, w0.w, w1.x, w1.y, w1.z, w1.w};
#pragma unroll
                for (int i = 0; i < 4; i++) {
                    float av = ((const float*)&a[i])[kk];
#pragma unroll
                    for (int j = 0; j < 8; j++)
                        acc[i][j] = fmaf(av, wv[j], acc[i][j]);
                }
            }
        }
        __syncthreads();
    }
#pragma unroll
    for (int i = 0; i < 4; i++) {
        int row = rbase + ty * 4 + i;
        if (row < N_NODES) {
            *(float4*)&T[row * HF + c0] = make_float4(acc[i][0], acc[i][1], acc[i][2], acc[i][3]);
            *(float4*)&T[row * HF + c1] = make_float4(acc[i][4], acc[i][5], acc[i][6], acc[i][7]);
        }
    }
}

// ---------------- aggregation: O[v] = lrelu(sum_e w_e * T[src_e]) ----------------
// one wave per node, float2/lane = full 128-feat row, branchless clamped unroll-16:
// avg degree 12 -> ~90% of nodes finish in ONE batch of 16 in-flight gathers.

__global__ __launch_bounds__(256) void agg_k(const float* __restrict__ T, float* __restrict__ O,
                                             const int* __restrict__ rowptr,
                                             const int2* __restrict__ edg) {
    int v = blockIdx.x * 4 + (threadIdx.x >> 6);
    if (v >= N_NODES) return;
    int lane = threadIdx.x & 63;
    int f = lane * 2;
    int e0 = __builtin_amdgcn_readfirstlane(rowptr[v]);
    int e1 = __builtin_amdgcn_readfirstlane(rowptr[v + 1]);
    float ax = 0.f, ay = 0.f;
    for (int e = e0; e < e1; e += 16) {
        int   s[16];
        float w[16];
#pragma unroll
        for (int u = 0; u < 16; u++) {
            int idx = e + u;
            bool ok = idx < e1;
            int2 ed = edg[ok ? idx : e0];
            s[u] = ed.x;
            w[u] = ok ? __int_as_float(ed.y) : 0.f;
        }
        float2 hv[16];
#pragma unroll
        for (int u = 0; u < 16; u++)
            hv[u] = *(const float2*)&T[(size_t)s[u] * HF + f];
#pragma unroll
        for (int u = 0; u < 16; u++) {
            ax = fmaf(hv[u].x, w[u], ax);
            ay = fmaf(hv[u].y, w[u], ay);
        }
    }
    *(float2*)&O[(size_t)v * HF + f] = make_float2(lrelu(ax), lrelu(ay));
}

// ---------------- output layer: out = H @ Wfc + bfc (N=4) ----------------

__global__ void fc_k(const float* __restrict__ H, const float* __restrict__ W,
                     const float* __restrict__ b, float* __restrict__ out) {
    int r = blockIdx.x * 256 + threadIdx.x;
    if (r >= N_NODES) return;
    float4 acc = *(const float4*)b;
    const float4* h4 = (const float4*)(H + r * HF);
    const float4* w4 = (const float4*)W;
#pragma unroll
    for (int k4 = 0; k4 < 32; k4++) {
        float4 hv = h4[k4];
        float4 wa = w4[k4 * 4 + 0], wb = w4[k4 * 4 + 1];
        float4 wc = w4[k4 * 4 + 2], wd = w4[k4 * 4 + 3];
        acc.x = fmaf(hv.x, wa.x, acc.x); acc.y = fmaf(hv.x, wa.y, acc.y);
        acc.z = fmaf(hv.x, wa.z, acc.z); acc.w = fmaf(hv.x, wa.w, acc.w);
        acc.x = fmaf(hv.y, wb.x, acc.x); acc.y = fmaf(hv.y, wb.y, acc.y);
        acc.z = fmaf(hv.y, wb.z, acc.z); acc.w = fmaf(hv.y, wb.w, acc.w);
        acc.x = fmaf(hv.z, wc.x, acc.x); acc.y = fmaf(hv.z, wc.y, acc.y);
        acc.z = fmaf(hv.z, wc.z, acc.z); acc.w = fmaf(hv.z, wc.w, acc.w);
        acc.x = fmaf(hv.w, wd.x, acc.x); acc.y = fmaf(hv.w, wd.y, acc.y);
        acc.z = fmaf(hv.w, wd.z, acc.z); acc.w = fmaf(hv.w, wd.w, acc.w);
    }
    *(float4*)&out[r * NC] = acc;
}

// ---------------- driver ----------------

extern "C" void kernel_launch(void* const* d_in, const int* in_sizes, int n_in,
                              void* d_out, int out_size, void* d_ws, size_t ws_size,
                              hipStream_t stream) {
    const float* X   = (const float*)d_in[0];
    const int*   EI  = (const int*)d_in[1];
    const float* EA  = (const float*)d_in[2];
    const float* Win = (const float*)d_in[3];
    const float* bin = (const float*)d_in[4];
    const float* Wh  = (const float*)d_in[5];
    const float* bh  = (const float*)d_in[6];
    const float* Wfc = (const float*)d_in[7];
    const float* bfc = (const float*)d_in[8];
    float* out = (float*)d_out;
    const int* src = EI;
    const int* dst = EI + N_EDGES;

    char* ws = (char*)d_ws;
    size_t off = 0;
    float* A    = (float*)(ws + off); off += (size_t)N_NODES * HF * 4;
    float* B    = (float*)(ws + off); off += (size_t)N_NODES * HF * 4;
    int2* edg   = (int2*)(ws + off);  off += (size_t)N_EDGES * 8;
    int* rowptr = (int*)(ws + off);   off += (((size_t)(N_NODES + 1) * 4 + 15) / 16) * 16;
    int* cnt    = (int*)(ws + off);   off += (size_t)N_NODES * 4;
    int* fill   = (int*)(ws + off);   off += (size_t)N_NODES * 4;
    float* dinv = (float*)(ws + off); off += (size_t)N_NODES * 4;

    hipMemsetAsync(cnt, 0, N_NODES * 4, stream);
    hipMemsetAsync(fill, 0, N_NODES * 4, stream);
    count_deg_k<<<(N_EDGES + 255) / 256, 256, 0, stream>>>(dst, cnt);
    deginv_k<<<(N_NODES + 255) / 256, 256, 0, stream>>>(cnt, dinv);
    scan_k<<<1, 1024, 0, stream>>>(cnt, rowptr);
    fill_k<<<(N_EDGES + 255) / 256, 256, 0, stream>>>(src, dst, EA, rowptr, fill, edg, dinv);

    gemm_in_k<<<(N_NODES + 15) / 16, 256, 0, stream>>>(X, Win, bin, B);
    agg_k<<<(N_NODES + 3) / 4, 256, 0, stream>>>(B, A, rowptr, edg);
    for (int l = 0; l < NHL; l++) {
        gemm_h_k<<<(N_NODES + 63) / 64, 256, 0, stream>>>(
            A, Wh + (size_t)l * HF * HF, bh + (size_t)l * HF, B);
        agg_k<<<(N_NODES + 3) / 4, 256, 0, stream>>>(B, A, rowptr, edg);
    }
    fc_k<<<(N_NODES + 255) / 256, 256, 0, stream>>>(A, Wfc, bfc, out);
}

// Round 6
// 1543.789 us; speedup vs baseline: 1.6174x; 1.0036x over previous
//
#include <hip/hip_runtime.h>

#define N_NODES 50000
#define N_EDGES 600000
#define IN_F 16
#define HF 128
#define NC 4
#define NHL 19
#define HS_STRIDE 36  // 32 k-chunk + pad; breaks power-of-2 LDS strides

__device__ __forceinline__ float lrelu(float x) { return x > 0.f ? x : 0.01f * x; }

// ---------------- CSR build ----------------

__global__ void count_deg_k(const int* __restrict__ dst, int* __restrict__ cnt) {
    int e = blockIdx.x * 256 + threadIdx.x;
    if (e < N_EDGES) atomicAdd(&cnt[dst[e]], 1);
}

__global__ void deginv_k(const int* __restrict__ cnt, float* __restrict__ dinv) {
    int v = blockIdx.x * 256 + threadIdx.x;
    if (v < N_NODES) dinv[v] = 1.0f / fmaxf((float)cnt[v], 1.0f);
}

// single-block exclusive scan via wave shuffles: 4 elements/thread, 4096/chunk
__global__ void scan_k(const int* __restrict__ cnt, int* __restrict__ rowptr) {
    __shared__ int wsum[16];
    __shared__ int carry_s;
    int t = threadIdx.x;
    int lane = t & 63, wid = t >> 6;
    if (t == 0) carry_s = 0;
    __syncthreads();
    for (int base = 0; base < N_NODES; base += 4096) {
        int idx = base + t * 4;
        int4 v = make_int4(0, 0, 0, 0);
        if (idx + 3 < N_NODES) v = *(const int4*)&cnt[idx];
        else {
            if (idx     < N_NODES) v.x = cnt[idx];
            if (idx + 1 < N_NODES) v.y = cnt[idx + 1];
            if (idx + 2 < N_NODES) v.z = cnt[idx + 2];
            if (idx + 3 < N_NODES) v.w = cnt[idx + 3];
        }
        int s1 = v.x + v.y, s2 = s1 + v.z, total = s2 + v.w;
        int sc = total;
#pragma unroll
        for (int off = 1; off < 64; off <<= 1) {
            int u = __shfl_up(sc, off, 64);
            if (lane >= off) sc += u;
        }
        if (lane == 63) wsum[wid] = sc;
        __syncthreads();
        if (t < 16) {
            int w = wsum[t];
#pragma unroll
            for (int off = 1; off < 16; off <<= 1) {
                int u = __shfl_up(w, off, 64);
                if (t >= off) w += u;
            }
            wsum[t] = w;
        }
        __syncthreads();
        int prefix = carry_s + (wid > 0 ? wsum[wid - 1] : 0) + (sc - total);
        if (idx     < N_NODES) rowptr[idx]     = prefix;
        if (idx + 1 < N_NODES) rowptr[idx + 1] = prefix + v.x;
        if (idx + 2 < N_NODES) rowptr[idx + 2] = prefix + s1;
        if (idx + 3 < N_NODES) rowptr[idx + 3] = prefix + s2;
        __syncthreads();
        if (t == 0) carry_s += wsum[15];
        __syncthreads();
    }
    if (t == 0) rowptr[N_NODES] = carry_s;
}

// fill CSR: one int2 {src, bitcast(ea*dinv[dst])} store per edge
__global__ void fill_k(const int* __restrict__ src, const int* __restrict__ dst,
                       const float* __restrict__ ea, const int* __restrict__ rowptr,
                       int* __restrict__ fill, int2* __restrict__ edg,
                       const float* __restrict__ dinv) {
    int e = blockIdx.x * 256 + threadIdx.x;
    if (e < N_EDGES) {
        int d = dst[e];
        int pos = rowptr[d] + atomicAdd(&fill[d], 1);
        edg[pos] = make_int2(src[e], __float_as_int(ea[e] * dinv[d]));
    }
}

// ---------------- input GEMM: T[50000x128] = X[50000x16] @ W[16x128] + b ----------------

__global__ void gemm_in_k(const float* __restrict__ X, const float* __restrict__ W,
                          const float* __restrict__ b, float* __restrict__ T) {
    __shared__ float Ws[IN_F * HF];  // 8 KB
    int t = threadIdx.x;
    ((float4*)Ws)[t]       = ((const float4*)W)[t];
    ((float4*)Ws)[t + 256] = ((const float4*)W)[t + 256];
    __syncthreads();
    int row = blockIdx.x * 16 + (t >> 4);
    if (row >= N_NODES) return;
    int tx = t & 15;
    int c0 = tx * 4, c1 = 64 + tx * 4;
    float4 a0 = *(const float4*)&b[c0];
    float4 a1 = *(const float4*)&b[c1];
    const float4* xr = (const float4*)(X + row * IN_F);
#pragma unroll
    for (int k4 = 0; k4 < 4; k4++) {
        float4 xv = xr[k4];
        const float* xp = (const float*)&xv;
#pragma unroll
        for (int kk = 0; kk < 4; kk++) {
            int k = k4 * 4 + kk;
            float4 w0 = *(const float4*)&Ws[k * HF + c0];
            float4 w1 = *(const float4*)&Ws[k * HF + c1];
            float xs = xp[kk];
            a0.x = fmaf(xs, w0.x, a0.x); a0.y = fmaf(xs, w0.y, a0.y);
            a0.z = fmaf(xs, w0.z, a0.z); a0.w = fmaf(xs, w0.w, a0.w);
            a1.x = fmaf(xs, w1.x, a1.x); a1.y = fmaf(xs, w1.y, a1.y);
            a1.z = fmaf(xs, w1.z, a1.z); a1.w = fmaf(xs, w1.w, a1.w);
        }
    }
    *(float4*)&T[row * HF + c0] = a0;
    *(float4*)&T[row * HF + c1] = a1;
}

// ---------------- hidden GEMM: T = H @ W + b, 64x128 tile ----------------

__global__ __launch_bounds__(256) void gemm_h_k(const float* __restrict__ H,
                                                const float* __restrict__ W,
                                                const float* __restrict__ b,
                                                float* __restrict__ T) {
    __shared__ float Ws[32 * HF];         // 16 KB
    __shared__ float Hs[64 * HS_STRIDE];  // 9 KB
    int t = threadIdx.x;
    int tx = t & 15, ty = t >> 4;
    int rbase = blockIdx.x * 64;
    int c0 = tx * 4, c1 = 64 + tx * 4;
    float4 b0 = *(const float4*)&b[c0];
    float4 b1 = *(const float4*)&b[c1];
    float acc[4][8];
#pragma unroll
    for (int i = 0; i < 4; i++) {
        acc[i][0] = b0.x; acc[i][1] = b0.y; acc[i][2] = b0.z; acc[i][3] = b0.w;
        acc[i][4] = b1.x; acc[i][5] = b1.y; acc[i][6] = b1.z; acc[i][7] = b1.w;
    }
    int srow = t >> 2;   // 0..63
    int sc4  = t & 3;    // 0..3

    for (int kc = 0; kc < HF; kc += 32) {
        const float4* Wg = (const float4*)(W + kc * HF);
#pragma unroll
        for (int i = 0; i < 4; i++)
            ((float4*)Ws)[t + i * 256] = Wg[t + i * 256];
        {
            int row = rbase + srow;
            if (row >= N_NODES) row = N_NODES - 1;
            const float* hr = &H[(size_t)row * HF + kc];
            *(float4*)&Hs[srow * HS_STRIDE + sc4 * 4]      = *(const float4*)&hr[sc4 * 4];
            *(float4*)&Hs[srow * HS_STRIDE + 16 + sc4 * 4] = *(const float4*)&hr[16 + sc4 * 4];
        }
        __syncthreads();
#pragma unroll
        for (int kq = 0; kq < 8; kq++) {
            float4 a[4];
#pragma unroll
            for (int i = 0; i < 4; i++)
                a[i] = *(const float4*)&Hs[(ty * 4 + i) * HS_STRIDE + kq * 4];
#pragma unroll
            for (int kk = 0; kk < 4; kk++) {
                int k = kq * 4 + kk;
                float4 w0 = *(const float4*)&Ws[k * HF + c0];
                float4 w1 = *(const float4*)&Ws[k * HF + c1];
                float wv[8] = {w0.x, w0.y, w0.z, w0.w, w1.x, w1.y, w1.z, w1.w};
#pragma unroll
                for (int i = 0; i < 4; i++) {
                    float av = ((const float*)&a[i])[kk];
#pragma unroll
                    for (int j = 0; j < 8; j++)
                        acc[i][j] = fmaf(av, wv[j], acc[i][j]);
                }
            }
        }
        __syncthreads();
    }
#pragma unroll
    for (int i = 0; i < 4; i++) {
        int row = rbase + ty * 4 + i;
        if (row < N_NODES) {
            *(float4*)&T[row * HF + c0] = make_float4(acc[i][0], acc[i][1], acc[i][2], acc[i][3]);
            *(float4*)&T[row * HF + c1] = make_float4(acc[i][4], acc[i][5], acc[i][6], acc[i][7]);
        }
    }
}

// ---------------- aggregation: O[v] = lrelu(sum_e w_e * T[src_e]) ----------------
// TWO nodes per wave: lanes 0-31 = node vA (float4/lane = 128 feats), lanes 32-63 = node vB.
// One gather instr covers one edge of A + one edge of B (1024 B). Edge records loaded
// one-per-lane and redistributed via __shfl (bpermute).

__global__ __launch_bounds__(256) void agg2_k(const float* __restrict__ T, float* __restrict__ O,
                                              const int* __restrict__ rowptr,
                                              const int2* __restrict__ edg) {
    int gw = blockIdx.x * 4 + (threadIdx.x >> 6);  // wave id = node pair id
    int vA = gw * 2;
    if (vA >= N_NODES) return;
    int lane = threadIdx.x & 63;
    int half = lane >> 5;        // 0 = node vA, 1 = node vB
    int li   = lane & 31;        // feature group: li*4 .. li*4+3
    int fo   = li * 4;

    int rA = __builtin_amdgcn_readfirstlane(rowptr[vA]);
    int rM = __builtin_amdgcn_readfirstlane(rowptr[vA + 1]);
    int rB = __builtin_amdgcn_readfirstlane(rowptr[vA + 2]);
    int eBase = half ? rM : rA;
    int eEnd  = half ? rB : rM;
    int degmax = max(rM - rA, rB - rM);
    int nb = (degmax + 15) >> 4;

    float4 acc = make_float4(0.f, 0.f, 0.f, 0.f);

    for (int eb = 0; eb < nb; eb++) {
        // each lane loads one edge record for its half (records 0..15, duplicated li&15)
        int idx = eBase + eb * 16 + (li & 15);
        bool ok = idx < eEnd;
        int2 rec = edg[ok ? idx : 0];
        int   s_l = rec.x;
        float w_l = ok ? __int_as_float(rec.y) : 0.f;
        int sb = half << 5;  // shuffle source base for my half
#pragma unroll
        for (int g = 0; g < 2; g++) {
            int   ss[8];
            float ww[8];
#pragma unroll
            for (int u = 0; u < 8; u++) {
                int sl = sb + g * 8 + u;
                ss[u] = __shfl(s_l, sl, 64);
                ww[u] = __shfl(w_l, sl, 64);
            }
            float4 hv[8];
#pragma unroll
            for (int u = 0; u < 8; u++)
                hv[u] = *(const float4*)&T[(size_t)ss[u] * HF + fo];
#pragma unroll
            for (int u = 0; u < 8; u++) {
                acc.x = fmaf(hv[u].x, ww[u], acc.x);
                acc.y = fmaf(hv[u].y, ww[u], acc.y);
                acc.z = fmaf(hv[u].z, ww[u], acc.z);
                acc.w = fmaf(hv[u].w, ww[u], acc.w);
            }
        }
    }
    int v = vA + half;
    *(float4*)&O[(size_t)v * HF + fo] =
        make_float4(lrelu(acc.x), lrelu(acc.y), lrelu(acc.z), lrelu(acc.w));
}

// ---------------- output layer: out = H @ Wfc + bfc (N=4) ----------------

__global__ void fc_k(const float* __restrict__ H, const float* __restrict__ W,
                     const float* __restrict__ b, float* __restrict__ out) {
    int r = blockIdx.x * 256 + threadIdx.x;
    if (r >= N_NODES) return;
    float4 acc = *(const float4*)b;
    const float4* h4 = (const float4*)(H + r * HF);
    const float4* w4 = (const float4*)W;
#pragma unroll
    for (int k4 = 0; k4 < 32; k4++) {
        float4 hv = h4[k4];
        float4 wa = w4[k4 * 4 + 0], wb = w4[k4 * 4 + 1];
        float4 wc = w4[k4 * 4 + 2], wd = w4[k4 * 4 + 3];
        acc.x = fmaf(hv.x, wa.x, acc.x); acc.y = fmaf(hv.x, wa.y, acc.y);
        acc.z = fmaf(hv.x, wa.z, acc.z); acc.w = fmaf(hv.x, wa.w, acc.w);
        acc.x = fmaf(hv.y, wb.x, acc.x); acc.y = fmaf(hv.y, wb.y, acc.y);
        acc.z = fmaf(hv.y, wb.z, acc.z); acc.w = fmaf(hv.y, wb.w, acc.w);
        acc.x = fmaf(hv.z, wc.x, acc.x); acc.y = fmaf(hv.z, wc.y, acc.y);
        acc.z = fmaf(hv.z, wc.z, acc.z); acc.w = fmaf(hv.z, wc.w, acc.w);
        acc.x = fmaf(hv.w, wd.x, acc.x); acc.y = fmaf(hv.w, wd.y, acc.y);
        acc.z = fmaf(hv.w, wd.z, acc.z); acc.w = fmaf(hv.w, wd.w, acc.w);
    }
    *(float4*)&out[r * NC] = acc;
}

// ---------------- driver ----------------

extern "C" void kernel_launch(void* const* d_in, const int* in_sizes, int n_in,
                              void* d_out, int out_size, void* d_ws, size_t ws_size,
                              hipStream_t stream) {
    const float* X   = (const float*)d_in[0];
    const int*   EI  = (const int*)d_in[1];
    const float* EA  = (const float*)d_in[2];
    const float* Win = (const float*)d_in[3];
    const float* bin = (const float*)d_in[4];
    const float* Wh  = (const float*)d_in[5];
    const float* bh  = (const float*)d_in[6];
    const float* Wfc = (const float*)d_in[7];
    const float* bfc = (const float*)d_in[8];
    float* out = (float*)d_out;
    const int* src = EI;
    const int* dst = EI + N_EDGES;

    char* ws = (char*)d_ws;
    size_t off = 0;
    float* A    = (float*)(ws + off); off += (size_t)N_NODES * HF * 4;
    float* B    = (float*)(ws + off); off += (size_t)N_NODES * HF * 4;
    int2* edg   = (int2*)(ws + off);  off += (size_t)N_EDGES * 8;
    int* rowptr = (int*)(ws + off);   off += (((size_t)(N_NODES + 1) * 4 + 15) / 16) * 16;
    int* cnt    = (int*)(ws + off);   off += (size_t)N_NODES * 4;
    int* fill   = (int*)(ws + off);   off += (size_t)N_NODES * 4;
    float* dinv = (float*)(ws + off); off += (size_t)N_NODES * 4;

    hipMemsetAsync(cnt, 0, N_NODES * 4, stream);
    hipMemsetAsync(fill, 0, N_NODES * 4, stream);
    count_deg_k<<<(N_EDGES + 255) / 256, 256, 0, stream>>>(dst, cnt);
    deginv_k<<<(N_NODES + 255) / 256, 256, 0, stream>>>(cnt, dinv);
    scan_k<<<1, 1024, 0, stream>>>(cnt, rowptr);
    fill_k<<<(N_EDGES + 255) / 256, 256, 0, stream>>>(src, dst, EA, rowptr, fill, edg, dinv);

    const int aggg = (N_NODES / 2 + 3) / 4;  // 2 nodes/wave, 4 waves/block

    gemm_in_k<<<(N_NODES + 15) / 16, 256, 0, stream>>>(X, Win, bin, B);
    agg2_k<<<aggg, 256, 0, stream>>>(B, A, rowptr, edg);
    for (int l = 0; l < NHL; l++) {
        gemm_h_k<<<(N_NODES + 63) / 64, 256, 0, stream>>>(
            A, Wh + (size_t)l * HF * HF, bh + (size_t)l * HF, B);
        agg2_k<<<aggg, 256, 0, stream>>>(B, A, rowptr, edg);
    }
    fc_k<<<(N_NODES + 255) / 256, 256, 0, stream>>>(A, Wfc, bfc, out);
}

// Round 7
// 1199.246 us; speedup vs baseline: 2.0821x; 1.2873x over previous
//
#include <hip/hip_runtime.h>
#include <hip/hip_fp16.h>

#define N_NODES 50000
#define N_EDGES 600000
#define IN_F 16
#define HF 128
#define NC 4
#define NHL 19
#define HS_STRIDE 36  // 32 k-chunk + pad; breaks power-of-2 LDS strides

__device__ __forceinline__ float lrelu(float x) { return x > 0.f ? x : 0.01f * x; }

struct h4 { __half2 a, b; };  // 8 bytes = 4 fp16 feats

// ---------------- CSR build ----------------

__global__ void count_deg_k(const int* __restrict__ dst, int* __restrict__ cnt) {
    int e = blockIdx.x * 256 + threadIdx.x;
    if (e < N_EDGES) atomicAdd(&cnt[dst[e]], 1);
}

__global__ void deginv_k(const int* __restrict__ cnt, float* __restrict__ dinv) {
    int v = blockIdx.x * 256 + threadIdx.x;
    if (v < N_NODES) dinv[v] = 1.0f / fmaxf((float)cnt[v], 1.0f);
}

// single-block exclusive scan via wave shuffles: 4 elements/thread, 4096/chunk
__global__ void scan_k(const int* __restrict__ cnt, int* __restrict__ rowptr) {
    __shared__ int wsum[16];
    __shared__ int carry_s;
    int t = threadIdx.x;
    int lane = t & 63, wid = t >> 6;
    if (t == 0) carry_s = 0;
    __syncthreads();
    for (int base = 0; base < N_NODES; base += 4096) {
        int idx = base + t * 4;
        int4 v = make_int4(0, 0, 0, 0);
        if (idx + 3 < N_NODES) v = *(const int4*)&cnt[idx];
        else {
            if (idx     < N_NODES) v.x = cnt[idx];
            if (idx + 1 < N_NODES) v.y = cnt[idx + 1];
            if (idx + 2 < N_NODES) v.z = cnt[idx + 2];
            if (idx + 3 < N_NODES) v.w = cnt[idx + 3];
        }
        int s1 = v.x + v.y, s2 = s1 + v.z, total = s2 + v.w;
        int sc = total;
#pragma unroll
        for (int off = 1; off < 64; off <<= 1) {
            int u = __shfl_up(sc, off, 64);
            if (lane >= off) sc += u;
        }
        if (lane == 63) wsum[wid] = sc;
        __syncthreads();
        if (t < 16) {
            int w = wsum[t];
#pragma unroll
            for (int off = 1; off < 16; off <<= 1) {
                int u = __shfl_up(w, off, 64);
                if (t >= off) w += u;
            }
            wsum[t] = w;
        }
        __syncthreads();
        int prefix = carry_s + (wid > 0 ? wsum[wid - 1] : 0) + (sc - total);
        if (idx     < N_NODES) rowptr[idx]     = prefix;
        if (idx + 1 < N_NODES) rowptr[idx + 1] = prefix + v.x;
        if (idx + 2 < N_NODES) rowptr[idx + 2] = prefix + s1;
        if (idx + 3 < N_NODES) rowptr[idx + 3] = prefix + s2;
        __syncthreads();
        if (t == 0) carry_s += wsum[15];
        __syncthreads();
    }
    if (t == 0) rowptr[N_NODES] = carry_s;
}

// fill CSR: one int2 {src, bitcast(ea*dinv[dst])} store per edge
__global__ void fill_k(const int* __restrict__ src, const int* __restrict__ dst,
                       const float* __restrict__ ea, const int* __restrict__ rowptr,
                       int* __restrict__ fill, int2* __restrict__ edg,
                       const float* __restrict__ dinv) {
    int e = blockIdx.x * 256 + threadIdx.x;
    if (e < N_EDGES) {
        int d = dst[e];
        int pos = rowptr[d] + atomicAdd(&fill[d], 1);
        edg[pos] = make_int2(src[e], __float_as_int(ea[e] * dinv[d]));
    }
}

// ---------------- input GEMM: Th[50000x128](fp16) = X[50000x16] @ W[16x128] + b ----------------

__global__ void gemm_in_k(const float* __restrict__ X, const float* __restrict__ W,
                          const float* __restrict__ b, h4* __restrict__ Th) {
    __shared__ float Ws[IN_F * HF];  // 8 KB
    int t = threadIdx.x;
    ((float4*)Ws)[t]       = ((const float4*)W)[t];
    ((float4*)Ws)[t + 256] = ((const float4*)W)[t + 256];
    __syncthreads();
    int row = blockIdx.x * 16 + (t >> 4);
    if (row >= N_NODES) return;
    int tx = t & 15;
    int c0 = tx * 4, c1 = 64 + tx * 4;
    float4 a0 = *(const float4*)&b[c0];
    float4 a1 = *(const float4*)&b[c1];
    const float4* xr = (const float4*)(X + row * IN_F);
#pragma unroll
    for (int k4 = 0; k4 < 4; k4++) {
        float4 xv = xr[k4];
        const float* xp = (const float*)&xv;
#pragma unroll
        for (int kk = 0; kk < 4; kk++) {
            int k = k4 * 4 + kk;
            float4 w0 = *(const float4*)&Ws[k * HF + c0];
            float4 w1 = *(const float4*)&Ws[k * HF + c1];
            float xs = xp[kk];
            a0.x = fmaf(xs, w0.x, a0.x); a0.y = fmaf(xs, w0.y, a0.y);
            a0.z = fmaf(xs, w0.z, a0.z); a0.w = fmaf(xs, w0.w, a0.w);
            a1.x = fmaf(xs, w1.x, a1.x); a1.y = fmaf(xs, w1.y, a1.y);
            a1.z = fmaf(xs, w1.z, a1.z); a1.w = fmaf(xs, w1.w, a1.w);
        }
    }
    h4 o0; o0.a = __floats2half2_rn(a0.x, a0.y); o0.b = __floats2half2_rn(a0.z, a0.w);
    h4 o1; o1.a = __floats2half2_rn(a1.x, a1.y); o1.b = __floats2half2_rn(a1.z, a1.w);
    Th[((size_t)row * HF + c0) >> 2] = o0;
    Th[((size_t)row * HF + c1) >> 2] = o1;
}

// ---------------- hidden GEMM: T = H @ W + b, 64x128 tile; fp16 or fp32 output ----------------

template <bool F16OUT>
__global__ __launch_bounds__(256) void gemm_h_k(const float* __restrict__ H,
                                                const float* __restrict__ W,
                                                const float* __restrict__ b,
                                                float* __restrict__ Tf,
                                                h4* __restrict__ Th) {
    __shared__ float Ws[32 * HF];         // 16 KB
    __shared__ float Hs[64 * HS_STRIDE];  // 9 KB
    int t = threadIdx.x;
    int tx = t & 15, ty = t >> 4;
    int rbase = blockIdx.x * 64;
    int c0 = tx * 4, c1 = 64 + tx * 4;
    float4 b0 = *(const float4*)&b[c0];
    float4 b1 = *(const float4*)&b[c1];
    float acc[4][8];
#pragma unroll
    for (int i = 0; i < 4; i++) {
        acc[i][0] = b0.x; acc[i][1] = b0.y; acc[i][2] = b0.z; acc[i][3] = b0.w;
        acc[i][4] = b1.x; acc[i][5] = b1.y; acc[i][6] = b1.z; acc[i][7] = b1.w;
    }
    int srow = t >> 2;   // 0..63
    int sc4  = t & 3;    // 0..3

    for (int kc = 0; kc < HF; kc += 32) {
        const float4* Wg = (const float4*)(W + kc * HF);
#pragma unroll
        for (int i = 0; i < 4; i++)
            ((float4*)Ws)[t + i * 256] = Wg[t + i * 256];
        {
            int row = rbase + srow;
            if (row >= N_NODES) row = N_NODES - 1;
            const float* hr = &H[(size_t)row * HF + kc];
            *(float4*)&Hs[srow * HS_STRIDE + sc4 * 4]      = *(const float4*)&hr[sc4 * 4];
            *(float4*)&Hs[srow * HS_STRIDE + 16 + sc4 * 4] = *(const float4*)&hr[16 + sc4 * 4];
        }
        __syncthreads();
#pragma unroll
        for (int kq = 0; kq < 8; kq++) {
            float4 a[4];
#pragma unroll
            for (int i = 0; i < 4; i++)
                a[i] = *(const float4*)&Hs[(ty * 4 + i) * HS_STRIDE + kq * 4];
#pragma unroll
            for (int kk = 0; kk < 4; kk++) {
                int k = kq * 4 + kk;
                float4 w0 = *(const float4*)&Ws[k * HF + c0];
                float4 w1 = *(const float4*)&Ws[k * HF + c1];
                float wv[8] = {w0.x, w0.y, w0.z, w0.w, w1.x, w1.y, w1.z, w1.w};
#pragma unroll
                for (int i = 0; i < 4; i++) {
                    float av = ((const float*)&a[i])[kk];
#pragma unroll
                    for (int j = 0; j < 8; j++)
                        acc[i][j] = fmaf(av, wv[j], acc[i][j]);
                }
            }
        }
        __syncthreads();
    }
#pragma unroll
    for (int i = 0; i < 4; i++) {
        int row = rbase + ty * 4 + i;
        if (row < N_NODES) {
            if (F16OUT) {
                h4 o0; o0.a = __floats2half2_rn(acc[i][0], acc[i][1]);
                       o0.b = __floats2half2_rn(acc[i][2], acc[i][3]);
                h4 o1; o1.a = __floats2half2_rn(acc[i][4], acc[i][5]);
                       o1.b = __floats2half2_rn(acc[i][6], acc[i][7]);
                Th[((size_t)row * HF + c0) >> 2] = o0;
                Th[((size_t)row * HF + c1) >> 2] = o1;
            } else {
                *(float4*)&Tf[(size_t)row * HF + c0] =
                    make_float4(acc[i][0], acc[i][1], acc[i][2], acc[i][3]);
                *(float4*)&Tf[(size_t)row * HF + c1] =
                    make_float4(acc[i][4], acc[i][5], acc[i][6], acc[i][7]);
            }
        }
    }
}

// ---------------- aggregation (fp16 payload): O[v] = lrelu(sum_e w_e * Th[src_e]) --------
// TWO nodes per wave: lanes 0-31 = node vA (4 feats/lane), lanes 32-63 = node vB.
// One gather instr = 2 rows x 256 B. Edge records one-per-lane, redistributed via __shfl.

__global__ __launch_bounds__(256) void agg2_h_k(const h4* __restrict__ Th, float* __restrict__ O,
                                                const int* __restrict__ rowptr,
                                                const int2* __restrict__ edg) {
    int gw = blockIdx.x * 4 + (threadIdx.x >> 6);
    int vA = gw * 2;
    if (vA >= N_NODES) return;
    int lane = threadIdx.x & 63;
    int half = lane >> 5;
    int li   = lane & 31;
    int fo   = li * 4;

    int rA = __builtin_amdgcn_readfirstlane(rowptr[vA]);
    int rM = __builtin_amdgcn_readfirstlane(rowptr[vA + 1]);
    int rB = __builtin_amdgcn_readfirstlane(rowptr[vA + 2]);
    int eBase = half ? rM : rA;
    int eEnd  = half ? rB : rM;
    int degmax = max(rM - rA, rB - rM);
    int nb = (degmax + 15) >> 4;

    float4 acc = make_float4(0.f, 0.f, 0.f, 0.f);

    for (int eb = 0; eb < nb; eb++) {
        int idx = eBase + eb * 16 + (li & 15);
        bool ok = idx < eEnd;
        int2 rec = edg[ok ? idx : 0];
        int   s_l = rec.x;
        float w_l = ok ? __int_as_float(rec.y) : 0.f;
        int sb = half << 5;
#pragma unroll
        for (int g = 0; g < 2; g++) {
            int   ss[8];
            float ww[8];
#pragma unroll
            for (int u = 0; u < 8; u++) {
                int sl = sb + g * 8 + u;
                ss[u] = __shfl(s_l, sl, 64);
                ww[u] = __shfl(w_l, sl, 64);
            }
            h4 hv[8];
#pragma unroll
            for (int u = 0; u < 8; u++)
                hv[u] = Th[((size_t)ss[u] * HF + fo) >> 2];
#pragma unroll
            for (int u = 0; u < 8; u++) {
                float2 p0 = __half22float2(hv[u].a);
                float2 p1 = __half22float2(hv[u].b);
                acc.x = fmaf(p0.x, ww[u], acc.x);
                acc.y = fmaf(p0.y, ww[u], acc.y);
                acc.z = fmaf(p1.x, ww[u], acc.z);
                acc.w = fmaf(p1.y, ww[u], acc.w);
            }
        }
    }
    int v = vA + half;
    *(float4*)&O[(size_t)v * HF + fo] =
        make_float4(lrelu(acc.x), lrelu(acc.y), lrelu(acc.z), lrelu(acc.w));
}

// ---------------- aggregation (fp32 payload, last layers) ----------------

__global__ __launch_bounds__(256) void agg2_k(const float* __restrict__ T, float* __restrict__ O,
                                              const int* __restrict__ rowptr,
                                              const int2* __restrict__ edg) {
    int gw = blockIdx.x * 4 + (threadIdx.x >> 6);
    int vA = gw * 2;
    if (vA >= N_NODES) return;
    int lane = threadIdx.x & 63;
    int half = lane >> 5;
    int li   = lane & 31;
    int fo   = li * 4;

    int rA = __builtin_amdgcn_readfirstlane(rowptr[vA]);
    int rM = __builtin_amdgcn_readfirstlane(rowptr[vA + 1]);
    int rB = __builtin_amdgcn_readfirstlane(rowptr[vA + 2]);
    int eBase = half ? rM : rA;
    int eEnd  = half ? rB : rM;
    int degmax = max(rM - rA, rB - rM);
    int nb = (degmax + 15) >> 4;

    float4 acc = make_float4(0.f, 0.f, 0.f, 0.f);

    for (int eb = 0; eb < nb; eb++) {
        int idx = eBase + eb * 16 + (li & 15);
        bool ok = idx < eEnd;
        int2 rec = edg[ok ? idx : 0];
        int   s_l = rec.x;
        float w_l = ok ? __int_as_float(rec.y) : 0.f;
        int sb = half << 5;
#pragma unroll
        for (int g = 0; g < 2; g++) {
            int   ss[8];
            float ww[8];
#pragma unroll
            for (int u = 0; u < 8; u++) {
                int sl = sb + g * 8 + u;
                ss[u] = __shfl(s_l, sl, 64);
                ww[u] = __shfl(w_l, sl, 64);
            }
            float4 hv[8];
#pragma unroll
            for (int u = 0; u < 8; u++)
                hv[u] = *(const float4*)&T[(size_t)ss[u] * HF + fo];
#pragma unroll
            for (int u = 0; u < 8; u++) {
                acc.x = fmaf(hv[u].x, ww[u], acc.x);
                acc.y = fmaf(hv[u].y, ww[u], acc.y);
                acc.z = fmaf(hv[u].z, ww[u], acc.z);
                acc.w = fmaf(hv[u].w, ww[u], acc.w);
            }
        }
    }
    int v = vA + half;
    *(float4*)&O[(size_t)v * HF + fo] =
        make_float4(lrelu(acc.x), lrelu(acc.y), lrelu(acc.z), lrelu(acc.w));
}

// ---------------- output layer: out = H @ Wfc + bfc (N=4) ----------------

__global__ void fc_k(const float* __restrict__ H, const float* __restrict__ W,
                     const float* __restrict__ b, float* __restrict__ out) {
    int r = blockIdx.x * 256 + threadIdx.x;
    if (r >= N_NODES) return;
    float4 acc = *(const float4*)b;
    const float4* h4p = (const float4*)(H + r * HF);
    const float4* w4 = (const float4*)W;
#pragma unroll
    for (int k4 = 0; k4 < 32; k4++) {
        float4 hv = h4p[k4];
        float4 wa = w4[k4 * 4 + 0], wb = w4[k4 * 4 + 1];
        float4 wc = w4[k4 * 4 + 2], wd = w4[k4 * 4 + 3];
        acc.x = fmaf(hv.x, wa.x, acc.x); acc.y = fmaf(hv.x, wa.y, acc.y);
        acc.z = fmaf(hv.x, wa.z, acc.z); acc.w = fmaf(hv.x, wa.w, acc.w);
        acc.x = fmaf(hv.y, wb.x, acc.x); acc.y = fmaf(hv.y, wb.y, acc.y);
        acc.z = fmaf(hv.y, wb.z, acc.z); acc.w = fmaf(hv.y, wb.w, acc.w);
        acc.x = fmaf(hv.z, wc.x, acc.x); acc.y = fmaf(hv.z, wc.y, acc.y);
        acc.z = fmaf(hv.z, wc.z, acc.z); acc.w = fmaf(hv.z, wc.w, acc.w);
        acc.x = fmaf(hv.w, wd.x, acc.x); acc.y = fmaf(hv.w, wd.y, acc.y);
        acc.z = fmaf(hv.w, wd.z, acc.z); acc.w = fmaf(hv.w, wd.w, acc.w);
    }
    *(float4*)&out[r * NC] = acc;
}

// ---------------- driver ----------------

extern "C" void kernel_launch(void* const* d_in, const int* in_sizes, int n_in,
                              void* d_out, int out_size, void* d_ws, size_t ws_size,
                              hipStream_t stream) {
    const float* X   = (const float*)d_in[0];
    const int*   EI  = (const int*)d_in[1];
    const float* EA  = (const float*)d_in[2];
    const float* Win = (const float*)d_in[3];
    const float* bin = (const float*)d_in[4];
    const float* Wh  = (const float*)d_in[5];
    const float* bh  = (const float*)d_in[6];
    const float* Wfc = (const float*)d_in[7];
    const float* bfc = (const float*)d_in[8];
    float* out = (float*)d_out;
    const int* src = EI;
    const int* dst = EI + N_EDGES;

    char* ws = (char*)d_ws;
    size_t off = 0;
    float* A    = (float*)(ws + off); off += (size_t)N_NODES * HF * 4;   // O, fp32
    float* Tf   = (float*)(ws + off); off += (size_t)N_NODES * HF * 4;   // T, fp32 (last layers)
    h4*    Th   = (h4*)(ws + off);    off += (size_t)N_NODES * HF * 2;   // T, fp16
    int2* edg   = (int2*)(ws + off);  off += (size_t)N_EDGES * 8;
    int* rowptr = (int*)(ws + off);   off += (((size_t)(N_NODES + 1) * 4 + 15) / 16) * 16;
    int* cnt    = (int*)(ws + off);   off += (size_t)N_NODES * 4;
    int* fill   = (int*)(ws + off);   off += (size_t)N_NODES * 4;
    float* dinv = (float*)(ws + off); off += (size_t)N_NODES * 4;

    hipMemsetAsync(cnt, 0, N_NODES * 4, stream);
    hipMemsetAsync(fill, 0, N_NODES * 4, stream);
    count_deg_k<<<(N_EDGES + 255) / 256, 256, 0, stream>>>(dst, cnt);
    deginv_k<<<(N_NODES + 255) / 256, 256, 0, stream>>>(cnt, dinv);
    scan_k<<<1, 1024, 0, stream>>>(cnt, rowptr);
    fill_k<<<(N_EDGES + 255) / 256, 256, 0, stream>>>(src, dst, EA, rowptr, fill, edg, dinv);

    const int aggg  = (N_NODES / 2 + 3) / 4;  // 2 nodes/wave, 4 waves/block
    const int gemmg = (N_NODES + 63) / 64;

    // layer 0: fp16 T
    gemm_in_k<<<(N_NODES + 15) / 16, 256, 0, stream>>>(X, Win, bin, Th);
    agg2_h_k<<<aggg, 256, 0, stream>>>(Th, A, rowptr, edg);
    // hidden layers 0..16: fp16 T (error from these is contracted ~0.58/layer downstream)
    for (int l = 0; l < NHL - 2; l++) {
        gemm_h_k<true><<<gemmg, 256, 0, stream>>>(
            A, Wh + (size_t)l * HF * HF, bh + (size_t)l * HF, Tf, Th);
        agg2_h_k<<<aggg, 256, 0, stream>>>(Th, A, rowptr, edg);
    }
    // last 2 hidden layers: fp32 T (protect final output precision)
    for (int l = NHL - 2; l < NHL; l++) {
        gemm_h_k<false><<<gemmg, 256, 0, stream>>>(
            A, Wh + (size_t)l * HF * HF, bh + (size_t)l * HF, Tf, Th);
        agg2_k<<<aggg, 256, 0, stream>>>(Tf, A, rowptr, edg);
    }
    fc_k<<<(N_NODES + 255) / 256, 256, 0, stream>>>(A, Wfc, bfc, out);
}

// Round 8
// 857.833 us; speedup vs baseline: 2.9107x; 1.3980x over previous
//
#include <hip/hip_runtime.h>
#include <hip/hip_fp16.h>

#define N_NODES 50000
#define N_EDGES 600000
#define IN_F 16
#define HF 128
#define NC 4
#define NHL 19
#define WS_STRIDE 136  // 128 f16 + 8 pad = 272 B rows: 4-bank shift/row, 16B-aligned

__device__ __forceinline__ float lrelu(float x) { return x > 0.f ? x : 0.01f * x; }

struct h4 { __half2 a, b; };  // 8 bytes = 4 fp16 feats

typedef _Float16 f16;
typedef _Float16 f16x8 __attribute__((ext_vector_type(8)));
typedef float    f32x4 __attribute__((ext_vector_type(4)));

// ---------------- CSR build ----------------

__global__ void count_deg_k(const int* __restrict__ dst, int* __restrict__ cnt) {
    int e = blockIdx.x * 256 + threadIdx.x;
    if (e < N_EDGES) atomicAdd(&cnt[dst[e]], 1);
}

__global__ void deginv_k(const int* __restrict__ cnt, float* __restrict__ dinv) {
    int v = blockIdx.x * 256 + threadIdx.x;
    if (v < N_NODES) dinv[v] = 1.0f / fmaxf((float)cnt[v], 1.0f);
}

// single-block exclusive scan via wave shuffles: 4 elements/thread, 4096/chunk
__global__ void scan_k(const int* __restrict__ cnt, int* __restrict__ rowptr) {
    __shared__ int wsum[16];
    __shared__ int carry_s;
    int t = threadIdx.x;
    int lane = t & 63, wid = t >> 6;
    if (t == 0) carry_s = 0;
    __syncthreads();
    for (int base = 0; base < N_NODES; base += 4096) {
        int idx = base + t * 4;
        int4 v = make_int4(0, 0, 0, 0);
        if (idx + 3 < N_NODES) v = *(const int4*)&cnt[idx];
        else {
            if (idx     < N_NODES) v.x = cnt[idx];
            if (idx + 1 < N_NODES) v.y = cnt[idx + 1];
            if (idx + 2 < N_NODES) v.z = cnt[idx + 2];
            if (idx + 3 < N_NODES) v.w = cnt[idx + 3];
        }
        int s1 = v.x + v.y, s2 = s1 + v.z, total = s2 + v.w;
        int sc = total;
#pragma unroll
        for (int off = 1; off < 64; off <<= 1) {
            int u = __shfl_up(sc, off, 64);
            if (lane >= off) sc += u;
        }
        if (lane == 63) wsum[wid] = sc;
        __syncthreads();
        if (t < 16) {
            int w = wsum[t];
#pragma unroll
            for (int off = 1; off < 16; off <<= 1) {
                int u = __shfl_up(w, off, 64);
                if (t >= off) w += u;
            }
            wsum[t] = w;
        }
        __syncthreads();
        int prefix = carry_s + (wid > 0 ? wsum[wid - 1] : 0) + (sc - total);
        if (idx     < N_NODES) rowptr[idx]     = prefix;
        if (idx + 1 < N_NODES) rowptr[idx + 1] = prefix + v.x;
        if (idx + 2 < N_NODES) rowptr[idx + 2] = prefix + s1;
        if (idx + 3 < N_NODES) rowptr[idx + 3] = prefix + s2;
        __syncthreads();
        if (t == 0) carry_s += wsum[15];
        __syncthreads();
    }
    if (t == 0) rowptr[N_NODES] = carry_s;
}

// fill CSR: one int2 {src, bitcast(ea*dinv[dst])} store per edge
__global__ void fill_k(const int* __restrict__ src, const int* __restrict__ dst,
                       const float* __restrict__ ea, const int* __restrict__ rowptr,
                       int* __restrict__ fill, int2* __restrict__ edg,
                       const float* __restrict__ dinv) {
    int e = blockIdx.x * 256 + threadIdx.x;
    if (e < N_EDGES) {
        int d = dst[e];
        int pos = rowptr[d] + atomicAdd(&fill[d], 1);
        edg[pos] = make_int2(src[e], __float_as_int(ea[e] * dinv[d]));
    }
}

// ---------------- W convert: Wh[l][k][n] fp32 -> Wt[l][n][k] fp16 (coalesced writes) -----

__global__ void wconv_k(const float* __restrict__ Wh, __half* __restrict__ Wt) {
    int idx = blockIdx.x * 256 + threadIdx.x;
    if (idx >= NHL * HF * HF) return;
    int l = idx / (HF * HF);
    int r = idx - l * (HF * HF);
    int n = r >> 7;   // output-major: n
    int k = r & 127;  // output-minor: k
    Wt[idx] = __float2half(Wh[(size_t)l * HF * HF + k * HF + n]);
}

// ---------------- input GEMM: Th[50000x128](fp16) = X[50000x16] @ W[16x128] + b ----------------

__global__ void gemm_in_k(const float* __restrict__ X, const float* __restrict__ W,
                          const float* __restrict__ b, h4* __restrict__ Th) {
    __shared__ float Ws[IN_F * HF];  // 8 KB
    int t = threadIdx.x;
    ((float4*)Ws)[t]       = ((const float4*)W)[t];
    ((float4*)Ws)[t + 256] = ((const float4*)W)[t + 256];
    __syncthreads();
    int row = blockIdx.x * 16 + (t >> 4);
    if (row >= N_NODES) return;
    int tx = t & 15;
    int c0 = tx * 4, c1 = 64 + tx * 4;
    float4 a0 = *(const float4*)&b[c0];
    float4 a1 = *(const float4*)&b[c1];
    const float4* xr = (const float4*)(X + row * IN_F);
#pragma unroll
    for (int k4 = 0; k4 < 4; k4++) {
        float4 xv = xr[k4];
        const float* xp = (const float*)&xv;
#pragma unroll
        for (int kk = 0; kk < 4; kk++) {
            int k = k4 * 4 + kk;
            float4 w0 = *(const float4*)&Ws[k * HF + c0];
            float4 w1 = *(const float4*)&Ws[k * HF + c1];
            float xs = xp[kk];
            a0.x = fmaf(xs, w0.x, a0.x); a0.y = fmaf(xs, w0.y, a0.y);
            a0.z = fmaf(xs, w0.z, a0.z); a0.w = fmaf(xs, w0.w, a0.w);
            a1.x = fmaf(xs, w1.x, a1.x); a1.y = fmaf(xs, w1.y, a1.y);
            a1.z = fmaf(xs, w1.z, a1.z); a1.w = fmaf(xs, w1.w, a1.w);
        }
    }
    h4 o0; o0.a = __floats2half2_rn(a0.x, a0.y); o0.b = __floats2half2_rn(a0.z, a0.w);
    h4 o1; o1.a = __floats2half2_rn(a1.x, a1.y); o1.b = __floats2half2_rn(a1.z, a1.w);
    Th[((size_t)row * HF + c0) >> 2] = o0;
    Th[((size_t)row * HF + c1) >> 2] = o1;
}

// ---------------- hidden GEMM via MFMA f16: T = H @ W + b ----------------
// H fp16 [M][128], Wt fp16 [n][k] (transposed), T fp16. 64 rows x 128 cols per block.
// A frag: lane holds A[m=lane&15][k=(lane>>4)*8+j]; B frag: B[k=(lane>>4)*8+j][n=lane&15].

__global__ __launch_bounds__(256) void gemm_mfma_k(const __half* __restrict__ H,
                                                   const __half* __restrict__ Wt,
                                                   const float* __restrict__ b,
                                                   __half* __restrict__ T) {
    __shared__ __half Ws[HF * WS_STRIDE];  // 34 KB, [n][k]
    __shared__ __half Hs[64 * WS_STRIDE];  // 17 KB, [row][k]; reused for output staging
    int t = threadIdx.x;
    int rbase = blockIdx.x * 64;
    int u16 = t & 15;   // 16B-unit within a 256B row
    int rg  = t >> 4;   // 0..15

    // stage W (128 rows x 256 B) and H (64 rows x 256 B), coalesced 16 B per thread
#pragma unroll
    for (int p = 0; p < 8; p++) {
        int n = p * 16 + rg;
        *(float4*)&Ws[n * WS_STRIDE + u16 * 8] = *(const float4*)&Wt[(size_t)n * HF + u16 * 8];
    }
#pragma unroll
    for (int p = 0; p < 4; p++) {
        int rl = p * 16 + rg;
        int row = rbase + rl;
        if (row >= N_NODES) row = N_NODES - 1;
        *(float4*)&Hs[rl * WS_STRIDE + u16 * 8] = *(const float4*)&H[(size_t)row * HF + u16 * 8];
    }
    __syncthreads();

    int lane = t & 63;
    int w    = t >> 6;        // wave id 0..3
    int wr   = w * 16;        // wave's row tile
    int m16  = lane & 15;
    int q    = lane >> 4;     // 0..3

    f16x8 af[4];
#pragma unroll
    for (int kc = 0; kc < 4; kc++)
        af[kc] = *(const f16x8*)&Hs[(wr + m16) * WS_STRIDE + kc * 32 + q * 8];

    f32x4 acc[8];
#pragma unroll
    for (int nt = 0; nt < 8; nt++) {
        float bv = b[nt * 16 + m16];
        acc[nt] = (f32x4){bv, bv, bv, bv};
#pragma unroll
        for (int kc = 0; kc < 4; kc++) {
            f16x8 bf = *(const f16x8*)&Ws[(nt * 16 + m16) * WS_STRIDE + kc * 32 + q * 8];
            acc[nt] = __builtin_amdgcn_mfma_f32_16x16x32_f16(af[kc], bf, acc[nt], 0, 0, 0);
        }
    }
    __syncthreads();  // all waves done reading Hs; reuse as output staging [row][n]

#pragma unroll
    for (int nt = 0; nt < 8; nt++)
#pragma unroll
        for (int r = 0; r < 4; r++)
            Hs[(wr + q * 4 + r) * WS_STRIDE + nt * 16 + m16] = __float2half(acc[nt][r]);
    __syncthreads();

#pragma unroll
    for (int p = 0; p < 4; p++) {
        int rl = p * 16 + rg;
        int row = rbase + rl;
        if (row < N_NODES)
            *(float4*)&T[(size_t)row * HF + u16 * 8] = *(float4*)&Hs[rl * WS_STRIDE + u16 * 8];
    }
}

// ---------------- aggregation (fp16 in, fp16 out): O[v] = lrelu(sum_e w_e * T[src_e]) ----
// TWO nodes per wave: lanes 0-31 = node vA (4 feats/lane), lanes 32-63 = node vB.

__global__ __launch_bounds__(256) void agg2_k(const h4* __restrict__ Th, h4* __restrict__ O,
                                              const int* __restrict__ rowptr,
                                              const int2* __restrict__ edg) {
    int gw = blockIdx.x * 4 + (threadIdx.x >> 6);
    int vA = gw * 2;
    if (vA >= N_NODES) return;
    int lane = threadIdx.x & 63;
    int half = lane >> 5;
    int li   = lane & 31;

    int rA = __builtin_amdgcn_readfirstlane(rowptr[vA]);
    int rM = __builtin_amdgcn_readfirstlane(rowptr[vA + 1]);
    int rB = __builtin_amdgcn_readfirstlane(rowptr[vA + 2]);
    int eBase = half ? rM : rA;
    int eEnd  = half ? rB : rM;
    int degmax = max(rM - rA, rB - rM);
    int nb = (degmax + 15) >> 4;

    float4 acc = make_float4(0.f, 0.f, 0.f, 0.f);

    for (int eb = 0; eb < nb; eb++) {
        int idx = eBase + eb * 16 + (li & 15);
        bool ok = idx < eEnd;
        int2 rec = edg[ok ? idx : 0];
        int   s_l = rec.x;
        float w_l = ok ? __int_as_float(rec.y) : 0.f;
        int sb = half << 5;
#pragma unroll
        for (int g = 0; g < 2; g++) {
            int   ss[8];
            float ww[8];
#pragma unroll
            for (int u = 0; u < 8; u++) {
                int sl = sb + g * 8 + u;
                ss[u] = __shfl(s_l, sl, 64);
                ww[u] = __shfl(w_l, sl, 64);
            }
            h4 hv[8];
#pragma unroll
            for (int u = 0; u < 8; u++)
                hv[u] = Th[(size_t)ss[u] * (HF / 4) + li];
#pragma unroll
            for (int u = 0; u < 8; u++) {
                float2 p0 = __half22float2(hv[u].a);
                float2 p1 = __half22float2(hv[u].b);
                acc.x = fmaf(p0.x, ww[u], acc.x);
                acc.y = fmaf(p0.y, ww[u], acc.y);
                acc.z = fmaf(p1.x, ww[u], acc.z);
                acc.w = fmaf(p1.y, ww[u], acc.w);
            }
        }
    }
    int v = vA + half;
    h4 o;
    o.a = __floats2half2_rn(lrelu(acc.x), lrelu(acc.y));
    o.b = __floats2half2_rn(lrelu(acc.z), lrelu(acc.w));
    O[(size_t)v * (HF / 4) + li] = o;
}

// ---------------- output layer: out = H(fp16) @ Wfc + bfc (N=4) ----------------

__global__ void fc_k(const __half* __restrict__ H, const float* __restrict__ W,
                     const float* __restrict__ b, float* __restrict__ out) {
    int r = blockIdx.x * 256 + threadIdx.x;
    if (r >= N_NODES) return;
    float4 acc = *(const float4*)b;
    const h4* hp = (const h4*)(H + (size_t)r * HF);
    const float4* w4 = (const float4*)W;
#pragma unroll
    for (int k4 = 0; k4 < 32; k4++) {
        h4 hh = hp[k4];
        float2 p0 = __half22float2(hh.a);
        float2 p1 = __half22float2(hh.b);
        float4 wa = w4[k4 * 4 + 0], wb = w4[k4 * 4 + 1];
        float4 wc = w4[k4 * 4 + 2], wd = w4[k4 * 4 + 3];
        acc.x = fmaf(p0.x, wa.x, acc.x); acc.y = fmaf(p0.x, wa.y, acc.y);
        acc.z = fmaf(p0.x, wa.z, acc.z); acc.w = fmaf(p0.x, wa.w, acc.w);
        acc.x = fmaf(p0.y, wb.x, acc.x); acc.y = fmaf(p0.y, wb.y, acc.y);
        acc.z = fmaf(p0.y, wb.z, acc.z); acc.w = fmaf(p0.y, wb.w, acc.w);
        acc.x = fmaf(p1.x, wc.x, acc.x); acc.y = fmaf(p1.x, wc.y, acc.y);
        acc.z = fmaf(p1.x, wc.z, acc.z); acc.w = fmaf(p1.x, wc.w, acc.w);
        acc.x = fmaf(p1.y, wd.x, acc.x); acc.y = fmaf(p1.y, wd.y, acc.y);
        acc.z = fmaf(p1.y, wd.z, acc.z); acc.w = fmaf(p1.y, wd.w, acc.w);
    }
    *(float4*)&out[r * NC] = acc;
}

// ---------------- driver ----------------

extern "C" void kernel_launch(void* const* d_in, const int* in_sizes, int n_in,
                              void* d_out, int out_size, void* d_ws, size_t ws_size,
                              hipStream_t stream) {
    const float* X   = (const float*)d_in[0];
    const int*   EI  = (const int*)d_in[1];
    const float* EA  = (const float*)d_in[2];
    const float* Win = (const float*)d_in[3];
    const float* bin = (const float*)d_in[4];
    const float* Wh  = (const float*)d_in[5];
    const float* bh  = (const float*)d_in[6];
    const float* Wfc = (const float*)d_in[7];
    const float* bfc = (const float*)d_in[8];
    float* out = (float*)d_out;
    const int* src = EI;
    const int* dst = EI + N_EDGES;

    char* ws = (char*)d_ws;
    size_t off = 0;
    __half* Oh  = (__half*)(ws + off); off += (size_t)N_NODES * HF * 2;   // 12.8 MB
    __half* Th  = (__half*)(ws + off); off += (size_t)N_NODES * HF * 2;   // 12.8 MB
    __half* Wt  = (__half*)(ws + off); off += (size_t)NHL * HF * HF * 2;  // 623 KB
    int2* edg   = (int2*)(ws + off);  off += (size_t)N_EDGES * 8;
    int* rowptr = (int*)(ws + off);   off += (((size_t)(N_NODES + 1) * 4 + 15) / 16) * 16;
    int* cnt    = (int*)(ws + off);   off += (size_t)N_NODES * 4;
    int* fill   = (int*)(ws + off);   off += (size_t)N_NODES * 4;
    float* dinv = (float*)(ws + off); off += (size_t)N_NODES * 4;

    hipMemsetAsync(cnt, 0, N_NODES * 4, stream);
    hipMemsetAsync(fill, 0, N_NODES * 4, stream);
    count_deg_k<<<(N_EDGES + 255) / 256, 256, 0, stream>>>(dst, cnt);
    deginv_k<<<(N_NODES + 255) / 256, 256, 0, stream>>>(cnt, dinv);
    scan_k<<<1, 1024, 0, stream>>>(cnt, rowptr);
    fill_k<<<(N_EDGES + 255) / 256, 256, 0, stream>>>(src, dst, EA, rowptr, fill, edg, dinv);
    wconv_k<<<(NHL * HF * HF + 255) / 256, 256, 0, stream>>>(Wh, Wt);

    const int aggg  = (N_NODES / 2 + 3) / 4;  // 2 nodes/wave, 4 waves/block
    const int gemmg = (N_NODES + 63) / 64;

    gemm_in_k<<<(N_NODES + 15) / 16, 256, 0, stream>>>(X, Win, bin, (h4*)Th);
    agg2_k<<<aggg, 256, 0, stream>>>((const h4*)Th, (h4*)Oh, rowptr, edg);
    for (int l = 0; l < NHL; l++) {
        gemm_mfma_k<<<gemmg, 256, 0, stream>>>(
            Oh, Wt + (size_t)l * HF * HF, bh + (size_t)l * HF, Th);
        agg2_k<<<aggg, 256, 0, stream>>>((const h4*)Th, (h4*)Oh, rowptr, edg);
    }
    fc_k<<<(N_NODES + 255) / 256, 256, 0, stream>>>(Oh, Wfc, bfc, out);
}